// Round 10
// baseline (36.916 us; speedup 1.0000x reference)
//
#include <hip/hip_runtime.h>

typedef __attribute__((ext_vector_type(8))) short bf16x8;
typedef __attribute__((ext_vector_type(4))) float f32x4;

#define PATCHES 196
#define ROWS 588             // 196 patches * 3 channels
#define NCHUNK 10            // ceil(588/64) row-chunks per batch
#define SCORE_B_STRIDE 5376  // 128*3*14 floats

// pack two f32 -> two bf16 (RNE) in one u32
static __device__ __forceinline__ unsigned f2bf2(float a, float b) {
    union { float f; unsigned u; } x, y; x.f = a; y.f = b;
    unsigned lo = (x.u + 0x7FFFu + ((x.u >> 16) & 1u)) >> 16;
    unsigned hi = (y.u + 0x7FFFu + ((y.u >> 16) & 1u)) & 0xFFFF0000u;
    return lo | hi;
}

// ---- Kernel 1: BM build + score transpose (merged; no extra launch) ---------
// block (b, zb): BM k-half zb  AND  transpose of (zb? v_score : h_scores)[b]
__global__ __launch_bounds__(256) void bm_prep(
    const float* __restrict__ h_scores, // [B,128,3,14]
    const float* __restrict__ v_score,  // [B,128,3,14]
    const float* __restrict__ h_base,   // [B,128,16]
    const float* __restrict__ v_base,   // [B,128,16]
    uint4* __restrict__ bmv,            // [B,16,256] uint4 (8k-chunks)
    float* __restrict__ hsT,            // [B,42,128]
    float* __restrict__ vsT)            // [B,42,128]
{
    __shared__ float hbT[16][68];       // [m][k'] pad 68: 2-way max
    __shared__ float vbT[16][68];
    __shared__ float ld[128][45];       // score transpose tile, conflict-free read
    const int b = blockIdx.x, zb = blockIdx.y, t = threadIdx.x;

    const float* hg = h_base + (size_t)b * 2048 + zb * 1024;
    const float* vg = v_base + (size_t)b * 2048 + zb * 1024;
#pragma unroll
    for (int i = 0; i < 4; ++i) {
        const int idx = t + i * 256;    // k' = idx>>4, m = idx&15
        hbT[idx & 15][idx >> 4] = hg[idx];
        vbT[idx & 15][idx >> 4] = vg[idx];
    }
    const float* ssrc = (zb ? v_score : h_scores) + (size_t)b * SCORE_B_STRIDE;
#pragma unroll
    for (int i = 0; i < 21; ++i) {      // coalesced in: 5376 = 21*256
        const int idx = t + i * 256;
        ld[idx / 42][idx % 42] = ssrc[idx];
    }
    __syncthreads();

    // BM product for this k-half
    const int m = t >> 4, n = t & 15;   // mn = t
    uint4* dst = bmv + ((size_t)b * 16 + zb * 8) * 256 + t;
#pragma unroll
    for (int i = 0; i < 8; ++i) {
        const float* vp = &vbT[m][i * 8];
        const float* hp = &hbT[n][i * 8];
        float p[8];
#pragma unroll
        for (int j = 0; j < 8; ++j) p[j] = vp[j] * hp[j];
        uint4 u = { f2bf2(p[0],p[1]), f2bf2(p[2],p[3]),
                    f2bf2(p[4],p[5]), f2bf2(p[6],p[7]) };
        dst[i * 256] = u;
    }
    // transposed score out: [42][128], coalesced; j = col*128 + k
    float* sdst = (zb ? vsT : hsT) + (size_t)b * SCORE_B_STRIDE;
#pragma unroll
    for (int i = 0; i < 21; ++i) {
        const int j = t + i * 256;
        sdst[j] = ld[j & 127][j >> 7];
    }
}

// ---- Kernel 2: fused softmax-W (LDS) + MFMA GEMM (B from L2) ----------------
__global__ __launch_bounds__(256, 3) void patch_gemm(
    const float* __restrict__ hsT,      // [B,42,128]
    const float* __restrict__ vsT,      // [B,42,128]
    const uint4* __restrict__ bmv,
    float* __restrict__ out)            // [B,588,256]
{
    __shared__ __align__(16) char lds[16384];   // W: 64 rows x 256B, XOR-swizzled

    const int bid = blockIdx.x;
    const int xcd = bid & 7, rest = bid >> 3;   // bijective: b%8 == XCD == k1 writer
    const int b = (rest / NCHUNK) * 8 + xcd;
    const int chunk = rest % NCHUNK;
    const int t = threadIdx.x;

    // ---- softmax: thread = (row r = t>>2, k-quarter kq = t&3); f32x4 loads ----
    {
        const int r = t >> 2, kq = t & 3;
        const int grow = chunk * 64 + r;
        const int geff = grow < ROWS ? grow : ROWS - 1;  // clamp; masked at store
        const int p = geff / 3, c = geff - p * 3;
        const int np = p / 14, mp = p - np * 14;
        const f32x4* hrow = (const f32x4*)(hsT + (size_t)b * SCORE_B_STRIDE
                                               + (c * 14 + np) * 128 + kq * 32);
        const f32x4* vrow = (const f32x4*)(vsT + (size_t)b * SCORE_B_STRIDE
                                               + (c * 14 + mp) * 128 + kq * 32);
        float sc[32];
#pragma unroll
        for (int j4 = 0; j4 < 8; ++j4) {
            f32x4 h4 = hrow[j4], v4 = vrow[j4];
#pragma unroll
            for (int e = 0; e < 4; ++e) sc[j4 * 4 + e] = h4[e] * v4[e];
        }
        float mx = sc[0];
#pragma unroll
        for (int j = 1; j < 32; ++j) mx = fmaxf(mx, sc[j]);
        mx = fmaxf(mx, __shfl_xor(mx, 1));
        mx = fmaxf(mx, __shfl_xor(mx, 2));
        float sum = 0.f;
#pragma unroll
        for (int j = 0; j < 32; ++j) { sc[j] = __expf(sc[j] - mx); sum += sc[j]; }
        sum += __shfl_xor(sum, 1);
        sum += __shfl_xor(sum, 2);
        const float inv = 1.f / sum;

        const int sw = (r & 7) << 4;
#pragma unroll
        for (int s2 = 0; s2 < 4; ++s2) {
            const int kpos = (kq * 32 + s2 * 8) * 2;     // byte offset of k0
            uint4 u = { f2bf2(sc[s2*8+0]*inv, sc[s2*8+1]*inv),
                        f2bf2(sc[s2*8+2]*inv, sc[s2*8+3]*inv),
                        f2bf2(sc[s2*8+4]*inv, sc[s2*8+5]*inv),
                        f2bf2(sc[s2*8+6]*inv, sc[s2*8+7]*inv) };
            *(uint4*)(lds + r * 256 + (kpos ^ sw)) = u;
        }
    }
    __syncthreads();

    // ---- MFMA: wave w owns rows [wrh*32,+32) and mn-half wnh*128 ----
    const int w = t >> 6, lane = t & 63;
    const int wrh = w >> 1, wnh = w & 1;
    const int lr = lane & 15, lg = lane >> 4;

    bf16x8 wfrag[2][4];
#pragma unroll
    for (int mi = 0; mi < 2; ++mi) {
        const int r2 = wrh * 32 + mi * 16 + lr;
        const int sw = (r2 & 7) << 4;
#pragma unroll
        for (int kc = 0; kc < 4; ++kc)
            wfrag[mi][kc] = *(const bf16x8*)(lds + r2 * 256 + ((kc * 64 + lg * 16) ^ sw));
    }

    const uint4* lane_base = bmv + (size_t)b * 4096 + wnh * 128 + lr;

    f32x4 acc[2][8];
#pragma unroll
    for (int mi = 0; mi < 2; ++mi)
#pragma unroll
        for (int nt = 0; nt < 8; ++nt)
            acc[mi][nt] = (f32x4){0.f, 0.f, 0.f, 0.f};

    // D = BM x W^T (operand-swapped); kc-outer, register dbuf (verified R9)
    uint4 cur[4], nxt[4];
#pragma unroll
    for (int j = 0; j < 4; ++j)
        cur[j] = lane_base[(0 * 4 + lg) * 256 + j * 16];
#pragma unroll
    for (int g = 0; g < 8; ++g) {
        const int kc = g >> 1, h = g & 1;
        if (g < 7) {
            const int gn = g + 1, kn = gn >> 1, hn = gn & 1;
#pragma unroll
            for (int j = 0; j < 4; ++j)
                nxt[j] = lane_base[(kn * 4 + lg) * 256 + (hn * 4 + j) * 16];
        }
#pragma unroll
        for (int j = 0; j < 4; ++j) {
            const int nt = h * 4 + j;
            bf16x8 bfrag = *(bf16x8*)&cur[j];
            acc[0][nt] = __builtin_amdgcn_mfma_f32_16x16x32_bf16(bfrag, wfrag[0][kc], acc[0][nt], 0, 0, 0);
            acc[1][nt] = __builtin_amdgcn_mfma_f32_16x16x32_bf16(bfrag, wfrag[1][kc], acc[1][nt], 0, 0, 0);
        }
#pragma unroll
        for (int j = 0; j < 4; ++j) cur[j] = nxt[j];
    }

    // ---- store: lane holds D[mn = nt*16+lg*4+reg][outrow = tile+lr] ----
    float* ob = out + (size_t)b * (ROWS * 256);
#pragma unroll
    for (int mi = 0; mi < 2; ++mi) {
        const int gr = chunk * 64 + wrh * 32 + mi * 16 + lr;
        if (gr < ROWS) {
            float* orow = ob + (size_t)gr * 256 + wnh * 128 + lg * 4;
#pragma unroll
            for (int nt = 0; nt < 8; ++nt)
                __builtin_nontemporal_store(acc[mi][nt], (f32x4*)(orow + nt * 16));
        }
    }
}

extern "C" void kernel_launch(void* const* d_in, const int* in_sizes, int n_in,
                              void* d_out, int out_size, void* d_ws, size_t ws_size,
                              hipStream_t stream) {
    const float* h_scores = (const float*)d_in[0];
    const float* v_score  = (const float*)d_in[1];
    const float* h_base   = (const float*)d_in[2];
    const float* v_base   = (const float*)d_in[3];
    float* out = (float*)d_out;

    const int B = in_sizes[0] / SCORE_B_STRIDE;   // 128

    // ws: [0,8MB) bmv | hsT | vsT (f32, B*5376 each)
    uint4* bmv = (uint4*)d_ws;
    float* hsT = (float*)((char*)d_ws + (size_t)8 * 1024 * 1024);
    float* vsT = hsT + (size_t)B * SCORE_B_STRIDE;

    bm_prep<<<dim3(B, 2), 256, 0, stream>>>(h_scores, v_score, h_base, v_base, bmv, hsT, vsT);
    patch_gemm<<<B * NCHUNK, 256, 0, stream>>>(hsT, vsT, bmv, out);
}